// Round 11
// baseline (62.404 us; speedup 1.0000x reference)
//
#include <hip/hip_runtime.h>

#define NCH   256
#define FH    64
#define FW    64
#define OUT_H 7
#define OUT_W 7
#define WPB   4      // independent waves per block
#define MAXH  34     // max region rows
#define LDSW  40     // floats per LDS row (10 quads)

// DIAGNOSTIC ROUND: gridDim.y = 3 replicates every task 3x (byte-identical
// output stores from distinct blocks -> race-free, deterministic). Purpose:
// surface this kernel above the ~40us fill dispatches in rocprof top-5 and
// discriminate work-rate-bound (dur ~3x) vs fixed-floor (dur ~1x).
__global__ __launch_bounds__(256) void roipool_kernel(
    const float* __restrict__ fm,   // (B, C, H, W)
    const int*   __restrict__ rois, // (N, 5): b, x1, y1, x2, y2
    float*       __restrict__ out)  // (N, C, 7, 7)
{
    __shared__ __align__(16) float lds[WPB][MAXH][LDSW];  // 21760 B

    const int tid  = threadIdx.x;
    const int wv   = tid >> 6;
    const int lane = tid & 63;
    const int task = __builtin_amdgcn_readfirstlane(blockIdx.x * WPB + wv);
    const int n    = task >> 8;
    const int c    = task & 255;

    const int* r = rois + n * 5;    // scalar loads (task uniform)
    const int b  = r[0];
    const int x1 = r[1] >> 4;       // exact: x*(1/16.f) trunc, 0<=x<1024
    const int y1 = r[2] >> 4;
    const int x2 = r[3] >> 4;
    const int y2 = r[4] >> 4;
    const int h_roi = y2 - y1 + 1;  // 1..34
    const int w_roi = x2 - x1 + 1;  // 1..34, bins never empty
    const int qs  = x1 >> 2;        // first aligned quad of region rows
    const int qn  = (x2 >> 2) - qs + 1;   // quads per row, 1..10
    const int off = x1 & 3;         // LDS col of x1

    // Tight SCALAR band-span bounds: max span = q + T[r], T={0,1,2,2,2,2,2}
    const int hq = h_roi / 7, hr = h_roi - hq * 7;
    const int wq = w_roi / 7, wr = w_roi - wq * 7;
    const int hb  = hq + (hr == 0 ? 0 : (hr == 1 ? 1 : 2));   // 1..6
    const int wbn = wq + (wr == 0 ? 0 : (wr == 1 ? 1 : 2));   // 1..6

    // ---- stage: lane -> (row-group rr 0..5, quad qq 0..9) ----
    // ALL loads issued into registers first (one latency exposure), then writes.
    const int rg = lane / 10;            // 0..6
    const int rr = (rg == 6) ? 0 : rg;   // lanes 60..63 duplicate (benign)
    const int qq = lane - rg * 10;       // 0..9 (0..3 for lanes 60..63)
    const int passes = (h_roi + 5) / 6;  // scalar, 1..6

    const float4* srcq =
        (const float4*)(fm + (((size_t)(b * NCH + c)) << 12) + ((size_t)y1 << 6)) + qs;
    const bool qok = (qq < qn);

    float4 v0, v1, v2, v3, v4, v5;       // staged quads (conditionally live)
    int h0, h1, h2, h3, h4, h5;
    if (qok) {
        // clamped row index per pass; dup loads/writes benign (same data)
        h0 = rr;                                   // p=0 always
        v0 = srcq[h0 * (FW / 4) + qq];
        if (passes > 1) { h1 = rr + 6;  h1 = (h1 < h_roi) ? h1 : (h_roi - 1); v1 = srcq[h1 * (FW / 4) + qq]; }
        if (passes > 2) { h2 = rr + 12; h2 = (h2 < h_roi) ? h2 : (h_roi - 1); v2 = srcq[h2 * (FW / 4) + qq]; }
        if (passes > 3) { h3 = rr + 18; h3 = (h3 < h_roi) ? h3 : (h_roi - 1); v3 = srcq[h3 * (FW / 4) + qq]; }
        if (passes > 4) { h4 = rr + 24; h4 = (h4 < h_roi) ? h4 : (h_roi - 1); v4 = srcq[h4 * (FW / 4) + qq]; }
        if (passes > 5) { h5 = rr + 30; h5 = (h5 < h_roi) ? h5 : (h_roi - 1); v5 = srcq[h5 * (FW / 4) + qq]; }

        float4* ldsq = (float4*)&lds[wv][0][0];
        ldsq[h0 * (LDSW / 4) + qq] = v0;
        if (passes > 1) ldsq[h1 * (LDSW / 4) + qq] = v1;
        if (passes > 2) ldsq[h2 * (LDSW / 4) + qq] = v2;
        if (passes > 3) ldsq[h3 * (LDSW / 4) + qq] = v3;
        if (passes > 4) ldsq[h4 * (LDSW / 4) + qq] = v4;
        if (passes > 5) ldsq[h5 * (LDSW / 4) + qq] = v5;
    }
    // no barrier: same wave produces and consumes its LDS slice (lgkmcnt orders)

    // ---- compute: lane = cell; scalar-trip clamped reads (avg ~4x4, max 6x6) ----
    if (lane < OUT_H * OUT_W) {
        const int i = lane / OUT_W;
        const int j = lane - i * OUT_W;

        const int hs  = (i * h_roi) / OUT_H;
        const int he1 = ((i + 1) * h_roi + 6) / OUT_H - 1;        // last row
        const int ws  = (j * w_roi) / OUT_W + off;
        const int we1 = ((j + 1) * w_roi + 6) / OUT_W - 1 + off;  // last col

        int cb[6];                      // clamped cols, compile-time indexed
        #pragma unroll
        for (int bb = 0; bb < 6; ++bb) {
            const int w = ws + bb;
            cb[bb] = (w < we1) ? w : we1;
        }

        const float* tb = &lds[wv][0][0];
        float m = -INFINITY;
        #pragma unroll
        for (int a = 0; a < 6; ++a) {
            if (a < hb) {                            // SCALAR guard (sgpr hb)
                const int hh = (hs + a < he1) ? hs + a : he1;   // lane clamp
                const float* rp = tb + hh * LDSW;
                #pragma unroll
                for (int bb = 0; bb < 6; ++bb) {
                    if (bb < wbn)                    // SCALAR guard (sgpr wbn)
                        m = fmaxf(m, rp[cb[bb]]);
                }
            }
        }
        out[(size_t)task * (OUT_H * OUT_W) + lane] = m;  // 196 B contiguous/wave
    }
}

extern "C" void kernel_launch(void* const* d_in, const int* in_sizes, int n_in,
                              void* d_out, int out_size, void* d_ws, size_t ws_size,
                              hipStream_t stream) {
    const float* fm   = (const float*)d_in[0];
    const int*   rois = (const int*)d_in[1];
    float*       out  = (float*)d_out;

    const int N = in_sizes[1] / 5;            // 256 rois
    dim3 grid((N * NCH) / WPB, 3);            // y=3: 3x task replication (diagnostic)
    dim3 block(256);
    roipool_kernel<<<grid, block, 0, stream>>>(fm, rois, out);
}

// Round 12
// 41.482 us; speedup vs baseline: 1.5044x; 1.5044x over previous
//
#include <hip/hip_runtime.h>

#define NCH   256
#define FW    64
#define OUT_H 7
#define OUT_W 7

// ---- Kernel 1: transpose (B,C,H,W) -> (B,H*W,C) into workspace ----
// (validated in rounds 3/4)
__global__ __launch_bounds__(256) void transpose_kernel(
    const float* __restrict__ fm, float* __restrict__ fmT)
{
    __shared__ float tile[64][65];
    const int hw0 = blockIdx.x * 64;   // 64 tiles of hw
    const int c0  = blockIdx.y * 64;   // 4 tiles of c
    const int b   = blockIdx.z;        // 4 batches
    const int t   = threadIdx.x;
    const int x   = t & 63;
    const int y   = t >> 6;            // 0..3

    const float* src = fm + (((size_t)(b * NCH + c0)) << 12) + hw0;
    #pragma unroll
    for (int r = 0; r < 16; ++r) {
        const int cl = y + r * 4;
        tile[cl][x] = src[((size_t)cl << 12) + x];   // coalesced
    }
    __syncthreads();
    float* dst = fmT + ((size_t)((b << 12) + hw0)) * NCH + c0;
    #pragma unroll
    for (int r = 0; r < 16; ++r) {
        const int hwl = y + r * 4;
        dst[(size_t)hwl * NCH + x] = tile[x][hwl];   // coalesced, pad-65 conflict-free
    }
}

// ---- Kernel 2: block = (roi, 64-ch group); wave = cells; lane = channel ----
// All addressing scalar (SGPR); loads are 256B coalesced; output assembled in
// LDS and written as one contiguous 12.25KB range per block (no false sharing).
__global__ __launch_bounds__(256) void roipool_kernel(
    const float* __restrict__ fmT,   // (B, H*W, C)
    const int*   __restrict__ rois,  // (N,5): b,x1,y1,x2,y2
    float*       __restrict__ out)   // (N, C, 7, 7)
{
    __shared__ float mbuf[OUT_H * OUT_W][65];   // 12740 B

    const int tid  = threadIdx.x;
    const int lane = tid & 63;
    const int wvs  = __builtin_amdgcn_readfirstlane(tid >> 6);       // 0..3
    const int n    = __builtin_amdgcn_readfirstlane(blockIdx.x >> 2);
    const int c0   = __builtin_amdgcn_readfirstlane(blockIdx.x & 3) << 6;

    const int* r = rois + n * 5;        // scalar s_loads
    const int b  = r[0];
    const int x1 = r[1] >> 4;           // exact: x*(1/16.f) trunc, 0<=x<1024
    const int y1 = r[2] >> 4;
    const int x2 = r[3] >> 4;
    const int y2 = r[4] >> 4;
    const int h  = y2 - y1 + 1;         // 1..34
    const int w  = x2 - x1 + 1;         // 1..34, bins never empty

    // lane's channel column; all remaining address math is scalar
    const float* base = fmT + ((((size_t)b << 12)) << 8) + c0 + lane;

    for (int cell = wvs; cell < OUT_H * OUT_W; cell += 4) {   // wave-uniform
        const int i = (cell * 9363) >> 16;                    // cell / 7
        const int j = cell - i * 7;
        const int hs  = y1 + ((i * h * 9363) >> 16);                    // floor
        const int he1 = y1 + ((((i + 1) * h + 6) * 9363) >> 16) - 1;    // last row
        const int ws  = x1 + ((j * w * 9363) >> 16);
        const int we1 = x1 + ((((j + 1) * w + 6) * 9363) >> 16) - 1;    // last col
        const int hn = he1 - hs + 1;    // exact span, 1..6 (scalar)
        const int wn = we1 - ws + 1;    // exact span, 1..6 (scalar)

        // batched guarded loads into registers: one latency exposure per cell
        float v[36];
        #pragma unroll
        for (int a = 0; a < 6; ++a) {
            if (a < hn) {                                   // SCALAR guard
                const int hh = hs + a;
                #pragma unroll
                for (int bb = 0; bb < 6; ++bb) {
                    if (bb < wn)                            // SCALAR guard
                        v[a * 6 + bb] =
                            base[(size_t)((hh << 6) + (ws + bb)) << 8];
                }
            }
        }
        float m = -INFINITY;
        #pragma unroll
        for (int a = 0; a < 6; ++a) {
            if (a < hn) {
                #pragma unroll
                for (int bb = 0; bb < 6; ++bb) {
                    if (bb < wn) m = fmaxf(m, v[a * 6 + bb]);
                }
            }
        }
        mbuf[cell][lane] = m;           // stride-65: conflict-free
    }
    __syncthreads();

    // write block's contiguous 3136-float output range, fully coalesced
    float* o = out + (size_t)n * (NCH * OUT_H * OUT_W) + c0 * (OUT_H * OUT_W);
    #pragma unroll
    for (int k = 0; k < 13; ++k) {
        const int idx = k * 256 + tid;
        if (idx < 64 * OUT_H * OUT_W) {
            const int c    = (int)(((unsigned)idx * 85599u) >> 22);  // idx / 49
            const int cell = idx - c * 49;
            o[idx] = mbuf[cell][c];     // (cell+c) bank walk: <=2-way (free)
        }
    }
}

extern "C" void kernel_launch(void* const* d_in, const int* in_sizes, int n_in,
                              void* d_out, int out_size, void* d_ws, size_t ws_size,
                              hipStream_t stream) {
    const float* fm   = (const float*)d_in[0];
    const int*   rois = (const int*)d_in[1];
    float*       out  = (float*)d_out;
    float*       fmT  = (float*)d_ws;            // 16 MB scratch

    dim3 tgrid(FW * FW / 64, NCH / 64, 4);       // (64, 4, 4)
    transpose_kernel<<<tgrid, 256, 0, stream>>>(fm, fmT);

    const int N = in_sizes[1] / 5;               // 256 rois
    roipool_kernel<<<dim3(N * 4), 256, 0, stream>>>(fmT, rois, out);
}

// Round 13
// 35.637 us; speedup vs baseline: 1.7511x; 1.1640x over previous
//
#include <hip/hip_runtime.h>

#define NCH   256
#define OUT_H 7
#define OUT_W 7
#define WPB   4      // independent waves per block
#define BPAD  68     // floats per band row (64 + pad)

// Wave = (roi, channel). Lane = absolute x-column (W=64 = wave width!).
// Separable max: vertical band-max from global (full rows, zero per-element
// addressing), 7 band rows -> LDS (conflict-free, all lanes distinct), then
// horizontal clamped reads. All ROI bounds scalar -> scalar guards.
__global__ __launch_bounds__(256) void roipool_kernel(
    const float* __restrict__ fm,   // (B, C, H, W)
    const int*   __restrict__ rois, // (N, 5): b, x1, y1, x2, y2
    float*       __restrict__ out)  // (N, C, 7, 7)
{
    __shared__ float bands[WPB][OUT_H][BPAD];   // 7616 B/block

    const int tid  = threadIdx.x;
    const int wv   = tid >> 6;
    const int lane = tid & 63;
    const int task = __builtin_amdgcn_readfirstlane(blockIdx.x * WPB + wv);
    const int n    = task >> 8;
    const int c    = task & 255;

    const int* r = rois + n * 5;    // scalar s_loads (task uniform)
    const int b  = r[0];
    const int x1 = r[1] >> 4;       // exact: x*(1/16.f) trunc, 0<=x<1024
    const int y1 = r[2] >> 4;
    const int x2 = r[3] >> 4;
    const int y2 = r[4] >> 4;
    const int h  = y2 - y1 + 1;     // 1..34
    const int w  = x2 - x1 + 1;     // 1..34, bins never empty

    // lane's fixed column address; only scalar row offsets vary per load
    const float* plane = fm + (((size_t)(b * NCH + c)) << 12) + lane;

    // ---- vertical: 7 bands, scalar spans, full-width rows ----
    // magic /7: (x*9363)>>16 == x/7 exact for 0 <= x <= 244 range used here
    float* bw = &bands[wv][0][0];
    #pragma unroll
    for (int i = 0; i < OUT_H; ++i) {
        const int hs = y1 + ((i * h * 9363) >> 16);                 // abs row
        const int sp = y1 + ((((i + 1) * h + 6) * 9363) >> 16) - hs; // 1..6
        float m = plane[hs << 6];
        #pragma unroll
        for (int a = 1; a < 6; ++a) {
            if (a < sp)                         // SCALAR guard
                m = fmaxf(m, plane[(hs + a) << 6]);
        }
        bw[i * BPAD + lane] = m;                // 64 distinct addrs, 2-way free
    }
    // same-wave LDS RAW: force completion + no reordering (rule-18 insurance)
    asm volatile("s_waitcnt lgkmcnt(0)" ::: "memory");
    __builtin_amdgcn_sched_barrier(0);

    // ---- horizontal: lanes 0..48 = cells; <=6 clamped reads ----
    if (lane < OUT_H * OUT_W) {
        const int i = (lane * 9363) >> 16;      // lane / 7
        const int j = lane - i * 7;
        const int ws  = (j * w * 9363) >> 16;                     // rel col
        const int we1 = ((((j + 1) * w + 6) * 9363) >> 16) - 1;   // last rel col

        // tight scalar bound on w-span: wq + T[rem], T={0,1,2,2,2,2,2}
        const int wq = (w * 9363) >> 16;
        const int wr = w - wq * 7;
        const int wbn = wq + (wr == 0 ? 0 : (wr == 1 ? 1 : 2));   // 1..6

        const float* br = &bands[wv][0][0] + i * BPAD + x1;
        float m = br[ws];
        #pragma unroll
        for (int bb = 1; bb < 6; ++bb) {
            if (bb < wbn) {                     // SCALAR guard
                const int cc = (ws + bb < we1) ? ws + bb : we1;   // lane clamp
                m = fmaxf(m, br[cc]);
            }
        }
        out[(size_t)task * (OUT_H * OUT_W) + lane] = m;  // 196 B contiguous
    }
}

extern "C" void kernel_launch(void* const* d_in, const int* in_sizes, int n_in,
                              void* d_out, int out_size, void* d_ws, size_t ws_size,
                              hipStream_t stream) {
    const float* fm   = (const float*)d_in[0];
    const int*   rois = (const int*)d_in[1];
    float*       out  = (float*)d_out;

    const int N = in_sizes[1] / 5;            // 256 rois
    dim3 grid((N * NCH) / WPB);               // 16384 blocks
    dim3 block(256);
    roipool_kernel<<<grid, block, 0, stream>>>(fm, rois, out);
}